// Round 1
// baseline (117.371 us; speedup 1.0000x reference)
//
#include <hip/hip_runtime.h>

// Updater: B=4194304 sequential scan, 3 independent scalar recurrences
//   net' = sigmoid(10*(net + u - 0.5)), u = W*x + b, pred = x . net'
// Chunked-scan parallelization with certified warm-up:
//   map is monotone in net -> trajectories from 0 and 1 bracket the truth.
//   Dual-trajectory warm-up with wave-uniform early exit (-> single traj),
//   geometric global-memory backoff (rare) terminating at exact net0.
//
// R1 change vs 101.6us baseline: NO LDS STAGING. Each wave's x-window is
// ~13KB (threads overlap 2/3) -> L1-resident; staging + __syncthreads +
// bank-conflicted ds_read_b128 was pure overhead, and 49.5KB LDS capped
// occupancy at 3 blocks/CU, leaving a 256-block tail round at 1 wave/SIMD.
// Now: direct per-lane float4 global loads (16B-aligned by construction),
// __launch_bounds__(256,4) so all 1024 blocks are co-resident (4 waves/SIMD,
// no tail), manual prefetch across the early-exit warm loop, and a
// float4-vectorized backoff (was 3 scalar loads/step).

#if __has_builtin(__builtin_amdgcn_exp2f)
#define EXP2F(v) __builtin_amdgcn_exp2f(v)
#else
#define EXP2F(v) __expf(0.6931471805599453f * (v))
#endif

namespace {
constexpr int   BTOT   = 4194304;
constexpr int   CHUNK  = 16;                  // output steps per thread
constexpr int   BLOCK  = 256;
constexpr int   BSTEPS = BLOCK * CHUNK;       // 4096 steps per block
constexpr int   WARM   = 32;                  // warm-up window (steps)
constexpr int   GRID   = BTOT / BSTEPS;       // 1024 blocks
constexpr float KEXP   = -14.426950408889634f; // -10 * log2(e)
constexpr float EPS    = 1e-6f;
}

// sigmoid(10*(n+u-0.5)) = rcp(1 + exp2(KEXP*n + c)), c = (KEXP*W)x + KEXP*(b-.5)
#define CVALS(X0, X1, X2)                                                     \
  const float c0 = fmaf(kw00, (X0), fmaf(kw01, (X1), fmaf(kw02, (X2), kb0)));  \
  const float c1 = fmaf(kw10, (X0), fmaf(kw11, (X1), fmaf(kw12, (X2), kb1)));  \
  const float c2 = fmaf(kw20, (X0), fmaf(kw21, (X1), fmaf(kw22, (X2), kb2)));

#define SIG(N, C) __builtin_amdgcn_rcpf(1.0f + EXP2F(fmaf(KEXP, (N), (C))))

// dual-trajectory (bracket) step
#define US(X0, X1, X2)                                                        \
  do {                                                                        \
    CVALS(X0, X1, X2)                                                         \
    lo0 = SIG(lo0, c0); hi0 = SIG(hi0, c0);                                   \
    lo1 = SIG(lo1, c1); hi1 = SIG(hi1, c1);                                   \
    lo2 = SIG(lo2, c2); hi2 = SIG(hi2, c2);                                   \
  } while (0)

// single-trajectory step (no pred)
#define SS(X0, X1, X2)                                                        \
  do {                                                                        \
    CVALS(X0, X1, X2)                                                         \
    m0 = SIG(m0, c0); m1 = SIG(m1, c1); m2 = SIG(m2, c2);                     \
  } while (0)

// main step: advance + pred
#define MS(IDX, X0, X1, X2)                                                   \
  do {                                                                        \
    CVALS(X0, X1, X2)                                                         \
    m0 = SIG(m0, c0); m1 = SIG(m1, c1); m2 = SIG(m2, c2);                     \
    pr[(IDX)] = fmaf((X0), m0, fmaf((X1), m1, (X2) * m2));                    \
  } while (0)

__global__ __launch_bounds__(BLOCK, 4) void Updater_65395172049297_kernel(
    const float* __restrict__ x, const float* __restrict__ W,
    const float* __restrict__ bv, const float* __restrict__ n0v,
    float* __restrict__ out)
{
    const float kw00 = KEXP * W[0], kw01 = KEXP * W[1], kw02 = KEXP * W[2];
    const float kw10 = KEXP * W[3], kw11 = KEXP * W[4], kw12 = KEXP * W[5];
    const float kw20 = KEXP * W[6], kw21 = KEXP * W[7], kw22 = KEXP * W[8];
    const float kb0 = KEXP * (bv[0] - 0.5f);
    const float kb1 = KEXP * (bv[1] - 0.5f);
    const float kb2 = KEXP * (bv[2] - 0.5f);
    const float n00 = n0v[0], n01 = n0v[1], n02 = n0v[2];

    const long start = (long)blockIdx.x * BSTEPS + (long)threadIdx.x * CHUNK;
    const int  wl    = (int)((start < (long)WARM) ? start : (long)WARM);
    const bool exact = (start - wl) == 0;   // warm-up window reaches t=0
    const int  gw    = wl >> 2;             // warm groups of 4 steps

    // per-thread warm window base: 3*(start-wl) floats, multiple of 12 -> 16B aligned
    const float4* wp = reinterpret_cast<const float4*>(x + 3 * (start - wl));

    float lo0, lo1, lo2, hi0, hi1, hi2, m0, m1, m2;
    bool  conv = false;
    int   g    = 0;

    if (exact) {
        m0 = n00; m1 = n01; m2 = n02; conv = true;
    } else {
        lo0 = lo1 = lo2 = 0.0f; hi0 = hi1 = hi2 = 1.0f;
        float4 A = wp[0], B4 = wp[1], C4 = wp[2];
        while (g < gw) {
            // prefetch next group; always in-bounds (main window follows warm)
            const float4 An = wp[3 * g + 3], Bn = wp[3 * g + 4], Cn = wp[3 * g + 5];
            US(A.x, A.y, A.z);
            US(A.w, B4.x, B4.y);
            US(B4.z, B4.w, C4.x);
            US(C4.y, C4.z, C4.w);
            ++g;
            conv = ((hi0 - lo0) < EPS) & ((hi1 - lo1) < EPS) & ((hi2 - lo2) < EPS);
            if (__all(conv)) break;
            A = An; B4 = Bn; C4 = Cn;
        }
        if (conv) { m0 = 0.5f * (lo0 + hi0); m1 = 0.5f * (lo1 + hi1); m2 = 0.5f * (lo2 + hi2); }
    }

    if (conv) {
        // single-trajectory remainder of warm-up (global, L1-hot)
        for (; g < gw; ++g) {
            const float4 a4 = wp[3 * g], b4 = wp[3 * g + 1], c4 = wp[3 * g + 2];
            SS(a4.x, a4.y, a4.z);
            SS(a4.w, b4.x, b4.y);
            SS(b4.z, b4.w, c4.x);
            SS(c4.y, c4.z, c4.w);
        }
    } else {
        // rare certified backoff: extend warm-up 4x each attempt, float4 groups
        for (int at = 1; at < 10 && !conv; ++at) {
            long wl2 = (long)WARM << (2 * at);
            long bgn = start - wl2;               // multiple of 4 (start mult 16, wl2 mult 4)
            bool ex2 = (bgn <= 0);
            if (ex2) bgn = 0;
            if (ex2) { lo0 = hi0 = n00; lo1 = hi1 = n01; lo2 = hi2 = n02; }
            else     { lo0 = lo1 = lo2 = 0.0f; hi0 = hi1 = hi2 = 1.0f; }
            const float4* bp = reinterpret_cast<const float4*>(x + 3 * bgn);
            const long ng = (start - bgn) >> 2;   // groups of 4 steps
            for (long q = 0; q < ng; ++q) {
                const float4 a4 = bp[3 * q], b4 = bp[3 * q + 1], c4 = bp[3 * q + 2];
                US(a4.x, a4.y, a4.z);
                US(a4.w, b4.x, b4.y);
                US(b4.z, b4.w, c4.x);
                US(c4.y, c4.z, c4.w);
            }
            conv = ex2 || (((hi0 - lo0) < EPS) & ((hi1 - lo1) < EPS) & ((hi2 - lo2) < EPS));
        }
        m0 = 0.5f * (lo0 + hi0); m1 = 0.5f * (lo1 + hi1); m2 = 0.5f * (lo2 + hi2);
    }

    // ---- main chunk: 16 steps, preds to registers ----
    const float4* mp = reinterpret_cast<const float4*>(x + 3 * start);
    float pr[CHUNK];
#pragma unroll
    for (int q = 0; q < CHUNK / 4; ++q) {
        const float4 a4 = mp[3 * q], b4 = mp[3 * q + 1], c4 = mp[3 * q + 2];
        MS(4 * q + 0, a4.x, a4.y, a4.z);
        MS(4 * q + 1, a4.w, b4.x, b4.y);
        MS(4 * q + 2, b4.z, b4.w, c4.x);
        MS(4 * q + 3, c4.y, c4.z, c4.w);
    }

    float4* op = reinterpret_cast<float4*>(out + start);
#pragma unroll
    for (int i = 0; i < CHUNK / 4; ++i)
        op[i] = make_float4(pr[4 * i + 0], pr[4 * i + 1], pr[4 * i + 2], pr[4 * i + 3]);
}

extern "C" void kernel_launch(void* const* d_in, const int* in_sizes, int n_in,
                              void* d_out, int out_size, void* d_ws, size_t ws_size,
                              hipStream_t stream) {
    const float* x   = (const float*)d_in[0];   // (B,1,3)
    const float* W   = (const float*)d_in[1];   // (3,3)
    const float* bv  = (const float*)d_in[2];   // (3,)
    const float* n0v = (const float*)d_in[3];   // (3,1)
    float*       out = (float*)d_out;           // (B,1)
    Updater_65395172049297_kernel<<<GRID, BLOCK, 0, stream>>>(x, W, bv, n0v, out);
}

// Round 2
// 103.285 us; speedup vs baseline: 1.1364x; 1.1364x over previous
//
#include <hip/hip_runtime.h>

// Updater: B=4194304 sequential scan, 3 independent scalar recurrences
//   net' = sigmoid(10*(net + u - 0.5)), u = W*x + b, pred = x . net'
// Chunked-scan parallelization with certified warm-up (monotone map ->
// trajectories from 0 and 1 bracket the truth; dual-trajectory warm-up with
// wave-uniform early exit; geometric global backoff, rare, exact at net0).
//
// R2 vs R1 (45us kernel) and R0 LDS baseline (~30us kernel):
//  - Main-chunk x (16 steps = 12 float4) gathered ONCE into registers.
//    Every 64B line is fully consumed by exactly one thread -> HBM fetch
//    = unique 50MB (R1's in-loop strided warm reads refetched 2x = 98MB).
//  - Warm-up x comes from NEIGHBOR LANES via ds_bpermute (lanes t-2, t-1
//    own those steps as their main chunks). Zero memory traffic for warm.
//  - Only wave-boundary lanes 0,1 read warm x from a tiny per-wave LDS
//    buffer (4 waves x 32 steps x float4 = 2KB total). No 49.5KB LDS, no
//    3-blocks/CU cap, no 768+256 two-round tail, no 32-way bank conflicts.
//  - __launch_bounds__(256,4): all 1024 blocks co-resident, single round.
//  - Block0/wave0 exact-start lanes: predicated warm variant taken by
//    exactly ONE wave in the whole grid (wave-uniform branch).

#if __has_builtin(__builtin_amdgcn_exp2f)
#define EXP2F(v) __builtin_amdgcn_exp2f(v)
#else
#define EXP2F(v) __expf(0.6931471805599453f * (v))
#endif

namespace {
constexpr int   BTOT   = 4194304;
constexpr int   CHUNK  = 16;                  // output steps per thread
constexpr int   BLOCK  = 256;
constexpr int   BSTEPS = BLOCK * CHUNK;       // 4096 steps per block
constexpr int   WARM   = 32;                  // warm-up window (steps)
constexpr int   GRID   = BTOT / BSTEPS;       // 1024 blocks
constexpr float KEXP   = -14.426950408889634f; // -10 * log2(e)
constexpr float EPS    = 1e-6f;
}

// sigmoid(10*(n+u-0.5)) = rcp(1 + exp2(KEXP*n + c)), c = (KEXP*W)x + KEXP*(b-.5)
#define CVALS(X0_, X1_, X2_)                                                   \
  const float c0 = fmaf(kw00, (X0_), fmaf(kw01, (X1_), fmaf(kw02, (X2_), kb0))); \
  const float c1 = fmaf(kw10, (X0_), fmaf(kw11, (X1_), fmaf(kw12, (X2_), kb1))); \
  const float c2 = fmaf(kw20, (X0_), fmaf(kw21, (X1_), fmaf(kw22, (X2_), kb2)));

#define SIG(N, C) __builtin_amdgcn_rcpf(1.0f + EXP2F(fmaf(KEXP, (N), (C))))

// lane-pull: value of (lane - d) for this wave, d preencoded as byte addr
#define PULL(VAL_, AD_)                                                        \
  __int_as_float(__builtin_amdgcn_ds_bpermute((AD_), __float_as_int(VAL_)))

// fetch warm-step S_'s x into X0,X1,X2: from neighbor-lane registers, with
// LDS boundary override for lane 0 (all s) and lane 1 (s<16).
#define WSTEP_FETCH(S_)                                                        \
  float X0, X1, X2;                                                            \
  {                                                                            \
    const int ad_ = ((S_) < 16) ? a2 : a1;                                     \
    X0 = PULL(fx[3 * ((S_) & 15) + 0], ad_);                                   \
    X1 = PULL(fx[3 * ((S_) & 15) + 1], ad_);                                   \
    X2 = PULL(fx[3 * ((S_) & 15) + 2], ad_);                                   \
    if (lane < (((S_) < 16) ? 2 : 1)) {                                        \
      const float4 wv = wbuf[w][lane * 16 + (S_)];                             \
      X0 = wv.x; X1 = wv.y; X2 = wv.z;                                         \
    }                                                                          \
  }

// dual-trajectory warm step (bracket). PRED_ is compile-time.
#define WSTEP_DUAL(S_, PRED_)                                                  \
  {                                                                            \
    WSTEP_FETCH(S_)                                                            \
    CVALS(X0, X1, X2)                                                          \
    const float a0_ = SIG(lo0, c0), b0_ = SIG(hi0, c0);                        \
    const float a1_ = SIG(lo1, c1), b1_ = SIG(hi1, c1);                        \
    const float a2_ = SIG(lo2, c2), b2_ = SIG(hi2, c2);                        \
    if (PRED_) {                                                               \
      const bool kp_ = (S_) >= smin;                                           \
      lo0 = kp_ ? a0_ : lo0; hi0 = kp_ ? b0_ : hi0;                            \
      lo1 = kp_ ? a1_ : lo1; hi1 = kp_ ? b1_ : hi1;                            \
      lo2 = kp_ ? a2_ : lo2; hi2 = kp_ ? b2_ : hi2;                            \
    } else {                                                                   \
      lo0 = a0_; hi0 = b0_; lo1 = a1_; hi1 = b1_; lo2 = a2_; hi2 = b2_;        \
    }                                                                          \
  }

// single-trajectory warm step
#define WSTEP_SNG(S_, PRED_)                                                   \
  {                                                                            \
    WSTEP_FETCH(S_)                                                            \
    CVALS(X0, X1, X2)                                                          \
    const float t0_ = SIG(m0, c0), t1_ = SIG(m1, c1), t2_ = SIG(m2, c2);       \
    if (PRED_) {                                                               \
      const bool kp_ = (S_) >= smin;                                           \
      m0 = kp_ ? t0_ : m0; m1 = kp_ ? t1_ : m1; m2 = kp_ ? t2_ : m2;           \
    } else {                                                                   \
      m0 = t0_; m1 = t1_; m2 = t2_;                                            \
    }                                                                          \
  }

#define WARM_GROUP(G_, PRED_)                                                  \
  if (!single) {                                                               \
    WSTEP_DUAL(4 * (G_) + 0, PRED_)                                            \
    WSTEP_DUAL(4 * (G_) + 1, PRED_)                                            \
    WSTEP_DUAL(4 * (G_) + 2, PRED_)                                            \
    WSTEP_DUAL(4 * (G_) + 3, PRED_)                                            \
    conv = ((hi0 - lo0) < EPS) & ((hi1 - lo1) < EPS) & ((hi2 - lo2) < EPS);    \
    if (__all(conv)) {                                                         \
      m0 = 0.5f * (lo0 + hi0); m1 = 0.5f * (lo1 + hi1); m2 = 0.5f * (lo2 + hi2); \
      single = true;                                                           \
    }                                                                          \
  } else {                                                                     \
    WSTEP_SNG(4 * (G_) + 0, PRED_)                                             \
    WSTEP_SNG(4 * (G_) + 1, PRED_)                                             \
    WSTEP_SNG(4 * (G_) + 2, PRED_)                                             \
    WSTEP_SNG(4 * (G_) + 3, PRED_)                                             \
  }

#define WARM_ALL(PRED_)                                                        \
  WARM_GROUP(0, PRED_) WARM_GROUP(1, PRED_) WARM_GROUP(2, PRED_)               \
  WARM_GROUP(3, PRED_) WARM_GROUP(4, PRED_) WARM_GROUP(5, PRED_)               \
  WARM_GROUP(6, PRED_) WARM_GROUP(7, PRED_)

// dual-trajectory backoff step (global x)
#define US(X0_, X1_, X2_)                                                      \
  do {                                                                         \
    CVALS(X0_, X1_, X2_)                                                       \
    lo0 = SIG(lo0, c0); hi0 = SIG(hi0, c0);                                    \
    lo1 = SIG(lo1, c1); hi1 = SIG(hi1, c1);                                    \
    lo2 = SIG(lo2, c2); hi2 = SIG(hi2, c2);                                    \
  } while (0)

// main step: advance + pred (x from registers)
#define MS(P_, X0_, X1_, X2_)                                                  \
  {                                                                            \
    CVALS(X0_, X1_, X2_)                                                       \
    m0 = SIG(m0, c0); m1 = SIG(m1, c1); m2 = SIG(m2, c2);                      \
    P_ = fmaf((X0_), m0, fmaf((X1_), m1, (X2_) * m2));                         \
  }

__global__ __launch_bounds__(BLOCK, 4) void Updater_65395172049297_kernel(
    const float* __restrict__ x, const float* __restrict__ W,
    const float* __restrict__ bv, const float* __restrict__ n0v,
    float* __restrict__ out)
{
    __shared__ float4 wbuf[BLOCK / 64][WARM];   // 4 waves x 32 steps = 2KB

    const float kw00 = KEXP * W[0], kw01 = KEXP * W[1], kw02 = KEXP * W[2];
    const float kw10 = KEXP * W[3], kw11 = KEXP * W[4], kw12 = KEXP * W[5];
    const float kw20 = KEXP * W[6], kw21 = KEXP * W[7], kw22 = KEXP * W[8];
    const float kb0 = KEXP * (bv[0] - 0.5f);
    const float kb1 = KEXP * (bv[1] - 0.5f);
    const float kb2 = KEXP * (bv[2] - 0.5f);
    const float n00 = n0v[0], n01 = n0v[1], n02 = n0v[2];

    const int  lane  = threadIdx.x & 63;
    const int  w     = threadIdx.x >> 6;
    const long S     = (long)blockIdx.x * BSTEPS;
    const long start = S + (long)threadIdx.x * CHUNK;

    // bpermute byte addresses for lane-2 / lane-1 pulls (clamped at wave edge)
    const int a2 = ((lane >= 2) ? (lane - 2) : lane) << 2;
    const int a1 = ((lane >= 1) ? (lane - 1) : lane) << 2;

    // ---- one-shot gather: this thread's 16-step x chunk into registers ----
    float fx[48];
    {
        const float4* mp = reinterpret_cast<const float4*>(x + 3 * start);
#pragma unroll
        for (int i = 0; i < 12; ++i) {
            const float4 v = mp[i];
            fx[4 * i + 0] = v.x; fx[4 * i + 1] = v.y;
            fx[4 * i + 2] = v.z; fx[4 * i + 3] = v.w;
        }
    }

    // ---- stage per-wave boundary window (32 steps before wave start) ----
    {
        const long wbase = S + (long)w * (64 * CHUNK);
        if (lane < WARM) {
            long sstep = wbase - WARM + lane;
            if (sstep < 0) sstep = 0;       // block0/wave0: values unused (exact lanes)
            const float* xp = x + 3 * sstep;
            wbuf[w][lane] = make_float4(xp[0], xp[1], xp[2], 0.0f);
        }
    }
    __syncthreads();

    // ---- warm-up: 32 steps, x via lane-pulls; dual bracket until __all ----
    const bool exact = (start <= (long)WARM);        // only block0/wave0 lanes 0..2
    const int  smin  = exact ? (int)(WARM - (int)start) : 0;  // skip s < smin
    const bool special = (blockIdx.x == 0) && (w == 0);

    float lo0, lo1, lo2, hi0, hi1, hi2;
    if (exact) { lo0 = hi0 = n00; lo1 = hi1 = n01; lo2 = hi2 = n02; }
    else       { lo0 = lo1 = lo2 = 0.0f; hi0 = hi1 = hi2 = 1.0f; }

    bool  conv = false, single = false;
    float m0 = n00, m1 = n01, m2 = n02;

    if (special) { WARM_ALL(true) } else { WARM_ALL(false) }

    if (!single) {
        if (!conv) {
            // rare certified backoff: extend window 4x per attempt (global x)
            for (int at = 1; at < 10 && !conv; ++at) {
                long wl2 = (long)WARM << (2 * at);
                long bgn = start - wl2;
                bool ex2 = (bgn <= 0);
                if (ex2) bgn = 0;
                if (ex2) { lo0 = hi0 = n00; lo1 = hi1 = n01; lo2 = hi2 = n02; }
                else     { lo0 = lo1 = lo2 = 0.0f; hi0 = hi1 = hi2 = 1.0f; }
                const float4* bp = reinterpret_cast<const float4*>(x + 3 * bgn);
                const long ng = (start - bgn) >> 2;   // groups of 4 steps
                for (long q = 0; q < ng; ++q) {
                    const float4 a4 = bp[3 * q], b4 = bp[3 * q + 1], c4 = bp[3 * q + 2];
                    US(a4.x, a4.y, a4.z);
                    US(a4.w, b4.x, b4.y);
                    US(b4.z, b4.w, c4.x);
                    US(c4.y, c4.z, c4.w);
                }
                conv = ex2 || (((hi0 - lo0) < EPS) & ((hi1 - lo1) < EPS) &
                               ((hi2 - lo2) < EPS));
            }
        }
        m0 = 0.5f * (lo0 + hi0); m1 = 0.5f * (lo1 + hi1); m2 = 0.5f * (lo2 + hi2);
    }

    // ---- main chunk: 16 steps from registers, store every 4 ----
    float4* op = reinterpret_cast<float4*>(out + start);
#pragma unroll
    for (int q = 0; q < 4; ++q) {
        float p0, p1, p2, p3;
        MS(p0, fx[12 * q + 0], fx[12 * q + 1], fx[12 * q + 2]);
        MS(p1, fx[12 * q + 3], fx[12 * q + 4], fx[12 * q + 5]);
        MS(p2, fx[12 * q + 6], fx[12 * q + 7], fx[12 * q + 8]);
        MS(p3, fx[12 * q + 9], fx[12 * q + 10], fx[12 * q + 11]);
        op[q] = make_float4(p0, p1, p2, p3);
    }
}

extern "C" void kernel_launch(void* const* d_in, const int* in_sizes, int n_in,
                              void* d_out, int out_size, void* d_ws, size_t ws_size,
                              hipStream_t stream) {
    const float* x   = (const float*)d_in[0];   // (B,1,3)
    const float* W   = (const float*)d_in[1];   // (3,3)
    const float* bv  = (const float*)d_in[2];   // (3,)
    const float* n0v = (const float*)d_in[3];   // (3,1)
    float*       out = (float*)d_out;           // (B,1)
    Updater_65395172049297_kernel<<<GRID, BLOCK, 0, stream>>>(x, W, bv, n0v, out);
}